// Round 17
// baseline (267.615 us; speedup 1.0000x reference)
//
#include <hip/hip_runtime.h>

#define B_ 2048
#define T_ 200
#define D_ 64

constexpr int NBLK = B_ / 16;  // 128 blocks, 2 waves each (consumer + producer)

typedef _Float16 half_t;
typedef __attribute__((ext_vector_type(4))) _Float16 h4;
typedef __attribute__((ext_vector_type(4))) float f32x4;

// v_mfma_f32_16x16x16_f16: D(16x16) = A(16x16)@B(16x16) + C
//   A: lane l holds A[row=l&15][k=(l>>4)*4+j], j=0..3
//   B: lane l holds B[k=(l>>4)*4+j][col=l&15]
//   D: lane l holds D[row=(l>>4)*4+r][col=l&15]
// KEY IDENTITY: D reg r and B half j address the SAME matrix element
// (index (l>>4)*4+i, col l&15). Computing the TRANSPOSED recurrence
// (A=W^T static, B=H^T state) makes each MFMA's output directly usable as
// the next MFMA's B operand after an in-lane f32->f16 cvt. No LDS exchange,
// no cross-lane ops on the serial chain.
__device__ __forceinline__ f32x4 MF16(h4 a, h4 b, f32x4 c) {
  return __builtin_amdgcn_mfma_f32_16x16x16f16(a, b, c, 0, 0, 0);
}

__device__ __forceinline__ float rcp_(float x) { return __builtin_amdgcn_rcpf(x); }
__device__ __forceinline__ float sigmoidf_(float x) { return rcp_(1.0f + __expf(-x)); }
__device__ __forceinline__ float tanhf_(float x) {
  x = fminf(fmaxf(x, -15.0f), 15.0f);
  const float e = __expf(2.0f * x);
  return (e - 1.0f) * rcp_(e + 1.0f);
}

// A-fragment loader: W^T tile. row (l&15) -> W column `col`; k (4q+j) -> W row.
__device__ __forceinline__ h4 loadA(const float* __restrict__ W, int stride,
                                    int k0, int col) {
  h4 v;
#pragma unroll
  for (int j = 0; j < 4; ++j) v[j] = (half_t)W[(k0 + j) * stride + col];
  return v;
}

#define FMK(F) \
  F(0,0) F(0,1) F(0,2) F(0,3) F(1,0) F(1,1) F(1,2) F(1,3) \
  F(2,0) F(2,1) F(2,2) F(2,3) F(3,0) F(3,1) F(3,2) F(3,3)

__global__ __launch_bounds__(128, 1)
void augru_tp(const float* __restrict__ X, const int* __restrict__ SL,
              const float* __restrict__ ATT, const float* __restrict__ Wg,
              const float* __restrict__ bg, const float* __restrict__ Wc,
              const float* __restrict__ bc, float* __restrict__ OUT) {
  // Double-buffered x-preactivations in D-layout: [buf][r|u|c][m][lane].
  __shared__ f32x4 sP[2][3][4][64];  // 24 KB

  const int tid = threadIdx.x;
  const int w = tid >> 6;   // 0 = consumer (recurrence), 1 = producer (x GEMM)
  const int l = tid & 63;
  const int q = l >> 4;     // k/row quarter
  const int bl = l & 15;    // batch column within the 16-batch group
  const int b0 = blockIdx.x * 16;

  int Lm = 1;
  for (int r = 0; r < 16; ++r) {
    const int v = SL[b0 + r];
    Lm = v > Lm ? v : Lm;
  }

  if (w == 1) {
    // ======================= PRODUCER WAVE ==================================
    // preact(t) = bias + W_x^T x(t)^T  (per gate r,u and candidate c)
#define DECLX(m, kk) h4 Xr##m##kk, Xu##m##kk, Xc##m##kk;
    FMK(DECLX)
#undef DECLX
#define INITX(m, kk)                                                \
  Xr##m##kk = loadA(Wg, 128, 16 * kk + 4 * q, 16 * m + bl);         \
  Xu##m##kk = loadA(Wg, 128, 16 * kk + 4 * q, 64 + 16 * m + bl);    \
  Xc##m##kk = loadA(Wc, 64, 16 * kk + 4 * q, 16 * m + bl);
    FMK(INITX)
#undef INITX

    const f32x4 br0 = *(const f32x4*)(bg + 0 + 4 * q);
    const f32x4 br1 = *(const f32x4*)(bg + 16 + 4 * q);
    const f32x4 br2 = *(const f32x4*)(bg + 32 + 4 * q);
    const f32x4 br3 = *(const f32x4*)(bg + 48 + 4 * q);
    const f32x4 bu0 = *(const f32x4*)(bg + 64 + 4 * q);
    const f32x4 bu1 = *(const f32x4*)(bg + 80 + 4 * q);
    const f32x4 bu2 = *(const f32x4*)(bg + 96 + 4 * q);
    const f32x4 bu3 = *(const f32x4*)(bg + 112 + 4 * q);
    const f32x4 bc0 = *(const f32x4*)(bc + 0 + 4 * q);
    const f32x4 bc1 = *(const f32x4*)(bc + 16 + 4 * q);
    const f32x4 bc2 = *(const f32x4*)(bc + 32 + 4 * q);
    const f32x4 bc3 = *(const f32x4*)(bc + 48 + 4 * q);

    const float* __restrict__ xrow = X + (size_t)(b0 + bl) * (T_ * D_);
    const f32x4 zf4 = {0.f, 0.f, 0.f, 0.f};

    // x(t) register block: xc[kk] = x[b=bl][16kk+4q .. +3]
    f32x4 xc0 = *(const f32x4*)(xrow + 0 + 4 * q);
    f32x4 xc1 = *(const f32x4*)(xrow + 16 + 4 * q);
    f32x4 xc2 = *(const f32x4*)(xrow + 32 + 4 * q);
    f32x4 xc3 = *(const f32x4*)(xrow + 48 + 4 * q);

#define PBODY(DSTBUF, TLOAD)                                               \
  {                                                                        \
    h4 xB0, xB1, xB2, xB3;                                                 \
    _Pragma("unroll") for (int j = 0; j < 4; ++j) {                        \
      xB0[j] = (half_t)xc0[j];                                             \
      xB1[j] = (half_t)xc1[j];                                             \
      xB2[j] = (half_t)xc2[j];                                             \
      xB3[j] = (half_t)xc3[j];                                             \
    }                                                                      \
    const int tl = (TLOAD);                                                \
    xc0 = *(const f32x4*)(xrow + tl * 64 + 0 + 4 * q);                     \
    xc1 = *(const f32x4*)(xrow + tl * 64 + 16 + 4 * q);                    \
    xc2 = *(const f32x4*)(xrow + tl * 64 + 32 + 4 * q);                    \
    xc3 = *(const f32x4*)(xrow + tl * 64 + 48 + 4 * q);                    \
    f32x4 rx0, rx1, rx2, rx3, ux0, ux1, ux2, ux3, cx0, cx1, cx2, cx3;      \
    rx0 = MF16(Xr01, xB1, MF16(Xr00, xB0, br0)) +                          \
          MF16(Xr03, xB3, MF16(Xr02, xB2, zf4));                           \
    rx1 = MF16(Xr11, xB1, MF16(Xr10, xB0, br1)) +                          \
          MF16(Xr13, xB3, MF16(Xr12, xB2, zf4));                           \
    rx2 = MF16(Xr21, xB1, MF16(Xr20, xB0, br2)) +                          \
          MF16(Xr23, xB3, MF16(Xr22, xB2, zf4));                           \
    rx3 = MF16(Xr31, xB1, MF16(Xr30, xB0, br3)) +                          \
          MF16(Xr33, xB3, MF16(Xr32, xB2, zf4));                           \
    ux0 = MF16(Xu01, xB1, MF16(Xu00, xB0, bu0)) +                          \
          MF16(Xu03, xB3, MF16(Xu02, xB2, zf4));                           \
    ux1 = MF16(Xu11, xB1, MF16(Xu10, xB0, bu1)) +                          \
          MF16(Xu13, xB3, MF16(Xu12, xB2, zf4));                           \
    ux2 = MF16(Xu21, xB1, MF16(Xu20, xB0, bu2)) +                          \
          MF16(Xu23, xB3, MF16(Xu22, xB2, zf4));                           \
    ux3 = MF16(Xu31, xB1, MF16(Xu30, xB0, bu3)) +                          \
          MF16(Xu33, xB3, MF16(Xu32, xB2, zf4));                           \
    cx0 = MF16(Xc01, xB1, MF16(Xc00, xB0, bc0)) +                          \
          MF16(Xc03, xB3, MF16(Xc02, xB2, zf4));                           \
    cx1 = MF16(Xc11, xB1, MF16(Xc10, xB0, bc1)) +                          \
          MF16(Xc13, xB3, MF16(Xc12, xB2, zf4));                           \
    cx2 = MF16(Xc21, xB1, MF16(Xc20, xB0, bc2)) +                          \
          MF16(Xc23, xB3, MF16(Xc22, xB2, zf4));                           \
    cx3 = MF16(Xc31, xB1, MF16(Xc30, xB0, bc3)) +                          \
          MF16(Xc33, xB3, MF16(Xc32, xB2, zf4));                           \
    sP[DSTBUF][0][0][l] = rx0; sP[DSTBUF][0][1][l] = rx1;                  \
    sP[DSTBUF][0][2][l] = rx2; sP[DSTBUF][0][3][l] = rx3;                  \
    sP[DSTBUF][1][0][l] = ux0; sP[DSTBUF][1][1][l] = ux1;                  \
    sP[DSTBUF][1][2][l] = ux2; sP[DSTBUF][1][3][l] = ux3;                  \
    sP[DSTBUF][2][0][l] = cx0; sP[DSTBUF][2][1][l] = cx1;                  \
    sP[DSTBUF][2][2][l] = cx2; sP[DSTBUF][2][3][l] = cx3;                  \
  }

    // prologue: preact(0) -> buf0; regs then hold x(1)
    PBODY(0, (1 < Lm) ? 1 : (Lm - 1));
    __syncthreads();
    for (int t = 0; t < Lm; ++t) {
      // regs hold x(t+1): compute preact(t+1) -> buf[(t+1)&1]; load x(t+2)
      PBODY((t + 1) & 1, (t + 2 < Lm) ? (t + 2) : (Lm - 1));
      __syncthreads();
    }
#undef PBODY
  } else {
    // ======================= CONSUMER WAVE (recurrence) =====================
#define DECLW(m, kk) h4 Ar##m##kk, Au##m##kk, Ac##m##kk;
    FMK(DECLW)
#undef DECLW
#define INITW(m, kk)                                                   \
  Ar##m##kk = loadA(Wg, 128, 64 + 16 * kk + 4 * q, 16 * m + bl);       \
  Au##m##kk = loadA(Wg, 128, 64 + 16 * kk + 4 * q, 64 + 16 * m + bl);  \
  Ac##m##kk = loadA(Wc, 64, 64 + 16 * kk + 4 * q, 16 * m + bl);
    FMK(INITW)
#undef INITW

    const int Lb = SL[b0 + bl];
    const float* __restrict__ attrow = ATT + (size_t)(b0 + bl) * T_;
    float* __restrict__ orow = OUT + (size_t)(b0 + bl) * (T_ * D_);
    const f32x4 zf4 = {0.f, 0.f, 0.f, 0.f};

    // state: hF[kk] (f32) and hB[kk] (f16 B-frags); d = 16kk + 4q + j
    f32x4 hF0 = zf4, hF1 = zf4, hF2 = zf4, hF3 = zf4;
    h4 hB0, hB1, hB2, hB3;
#pragma unroll
    for (int j = 0; j < 4; ++j) {
      hB0[j] = (half_t)0.f; hB1[j] = (half_t)0.f;
      hB2[j] = (half_t)0.f; hB3[j] = (half_t)0.f;
    }

    float a_cur = attrow[0];
    __syncthreads();  // matches producer prologue barrier

    for (int t = 0; t < Lm; ++t) {
      const int tb = t & 1;
      // issue all preact reads early (12 x ds_read_b128)
      const f32x4 pr0 = sP[tb][0][0][l], pr1 = sP[tb][0][1][l],
                  pr2 = sP[tb][0][2][l], pr3 = sP[tb][0][3][l];
      const f32x4 pu0 = sP[tb][1][0][l], pu1 = sP[tb][1][1][l],
                  pu2 = sP[tb][1][2][l], pu3 = sP[tb][1][3][l];
      const f32x4 pc0 = sP[tb][2][0][l], pc1 = sP[tb][2][1][l],
                  pc2 = sP[tb][2][2][l], pc3 = sP[tb][2][3][l];

      const int tn = (t + 1 < Lm) ? t + 1 : t;
      const float a_nxt = attrow[tn];

      // ---- r gates: depth-2 MFMA chains ----
      const f32x4 r0 = MF16(Ar01, hB1, MF16(Ar00, hB0, pr0)) +
                       MF16(Ar03, hB3, MF16(Ar02, hB2, zf4));
      const f32x4 r1 = MF16(Ar11, hB1, MF16(Ar10, hB0, pr1)) +
                       MF16(Ar13, hB3, MF16(Ar12, hB2, zf4));
      const f32x4 r2 = MF16(Ar21, hB1, MF16(Ar20, hB0, pr2)) +
                       MF16(Ar23, hB3, MF16(Ar22, hB2, zf4));
      const f32x4 r3 = MF16(Ar31, hB1, MF16(Ar30, hB0, pr3)) +
                       MF16(Ar33, hB3, MF16(Ar32, hB2, zf4));

      // ---- rh = sigmoid(r) * h, directly as next B-frags (in-lane!) ----
      h4 rh0, rh1, rh2, rh3;
#pragma unroll
      for (int j = 0; j < 4; ++j) {
        rh0[j] = (half_t)(sigmoidf_(r0[j]) * hF0[j]);
        rh1[j] = (half_t)(sigmoidf_(r1[j]) * hF1[j]);
        rh2[j] = (half_t)(sigmoidf_(r2[j]) * hF2[j]);
        rh3[j] = (half_t)(sigmoidf_(r3[j]) * hF3[j]);
      }

      // ---- candidate (on-chain) ----
      const f32x4 c0 = MF16(Ac01, rh1, MF16(Ac00, rh0, pc0)) +
                       MF16(Ac03, rh3, MF16(Ac02, rh2, zf4));
      const f32x4 c1 = MF16(Ac11, rh1, MF16(Ac10, rh0, pc1)) +
                       MF16(Ac13, rh3, MF16(Ac12, rh2, zf4));
      const f32x4 c2 = MF16(Ac21, rh1, MF16(Ac20, rh0, pc2)) +
                       MF16(Ac23, rh3, MF16(Ac22, rh2, zf4));
      const f32x4 c3 = MF16(Ac31, rh1, MF16(Ac30, rh0, pc3)) +
                       MF16(Ac33, rh3, MF16(Ac32, rh2, zf4));

      // ---- u gates (parallel to candidate) ----
      const f32x4 u0 = MF16(Au01, hB1, MF16(Au00, hB0, pu0)) +
                       MF16(Au03, hB3, MF16(Au02, hB2, zf4));
      const f32x4 u1 = MF16(Au11, hB1, MF16(Au10, hB0, pu1)) +
                       MF16(Au13, hB3, MF16(Au12, hB2, zf4));
      const f32x4 u2 = MF16(Au21, hB1, MF16(Au20, hB0, pu2)) +
                       MF16(Au23, hB3, MF16(Au22, hB2, zf4));
      const f32x4 u3 = MF16(Au31, hB1, MF16(Au30, hB0, pu3)) +
                       MF16(Au33, hB3, MF16(Au32, hB2, zf4));

      // ---- blend + mask + store + refresh fp16 state ----
      const bool okb = (t < Lb);  // depends only on this lane's batch row
#define BLEND(m)                                                            \
  {                                                                         \
    f32x4 hn;                                                               \
    _Pragma("unroll") for (int j = 0; j < 4; ++j) {                         \
      const float uv = sigmoidf_(u##m[j]);                                  \
      const float cv = tanhf_(c##m[j]);                                     \
      hn[j] = fmaf(a_cur * uv, cv - hF##m[j], hF##m[j]);                    \
    }                                                                       \
    hF##m = okb ? hn : hF##m;                                               \
    *(f32x4*)(orow + t * 64 + 16 * m + 4 * q) = okb ? hn : zf4;             \
    _Pragma("unroll") for (int j = 0; j < 4; ++j)                           \
        hB##m[j] = (half_t)hF##m[j];                                        \
  }
      BLEND(0) BLEND(1) BLEND(2) BLEND(3)
#undef BLEND

      __syncthreads();
      a_cur = a_nxt;
    }

    // zero-fill past the block's max length
    for (int t = Lm; t < T_; ++t) {
      *(f32x4*)(orow + t * 64 + 0 + 4 * q) = zf4;
      *(f32x4*)(orow + t * 64 + 16 + 4 * q) = zf4;
      *(f32x4*)(orow + t * 64 + 32 + 4 * q) = zf4;
      *(f32x4*)(orow + t * 64 + 48 + 4 * q) = zf4;
    }
  }
}

extern "C" void kernel_launch(void* const* d_in, const int* in_sizes, int n_in,
                              void* d_out, int out_size, void* d_ws, size_t ws_size,
                              hipStream_t stream) {
  (void)in_sizes; (void)n_in; (void)d_ws; (void)ws_size; (void)out_size;
  const float* X  = (const float*)d_in[0];
  const int*   SL = (const int*)d_in[1];
  const float* A  = (const float*)d_in[2];
  const float* Wg = (const float*)d_in[3];
  const float* bg = (const float*)d_in[4];
  const float* Wc = (const float*)d_in[5];
  const float* bc = (const float*)d_in[6];
  float* O = (float*)d_out;

  augru_tp<<<NBLK, 128, 0, stream>>>(X, SL, A, Wg, bg, Wc, bc, O);
}

// Round 18
// 128.672 us; speedup vs baseline: 2.0798x; 2.0798x over previous
//
#include <hip/hip_runtime.h>

#define B_ 2048
#define T_ 200
#define D_ 64

constexpr int NBLK = B_ / 16;  // 128 blocks, 8 waves each

typedef _Float16 half_t;
typedef __attribute__((ext_vector_type(8))) _Float16 h8;
typedef __attribute__((ext_vector_type(4))) float f32x4;

// 16x16x32 f16 MFMA fragment layouts [HW-verified r9/r11/r12]:
// A: lane l holds A[row=l&15][k=(l>>4)*8+j]
// B: lane l holds B[k=(l>>4)*8+j][col=l&15]
// C/D: lane l holds D[row=(l>>4)*4+reg][col=l&15]
__device__ __forceinline__ f32x4 MF(h8 a, h8 b, f32x4 c) {
  return __builtin_amdgcn_mfma_f32_16x16x32_f16(a, b, c, 0, 0, 0);
}

__device__ __forceinline__ float rcp_(float x) { return __builtin_amdgcn_rcpf(x); }
__device__ __forceinline__ float sigmoidf_(float x) { return rcp_(1.0f + __expf(-x)); }
__device__ __forceinline__ float tanhf_(float x) {
  x = fminf(fmaxf(x, -15.0f), 15.0f);
  const float e = __expf(2.0f * x);
  return (e - 1.0f) * rcp_(e + 1.0f);
}

__device__ __forceinline__ h8 loadB(const float* __restrict__ W, int stride,
                                    int k0, int col) {
  h8 v;
#pragma unroll
  for (int j = 0; j < 8; ++j) v[j] = (half_t)W[(k0 + j) * stride + col];
  return v;
}

// ROLE-SPLIT DESIGN: consumers carry the serial chain with ZERO global memory
// ops in-loop, so their __syncthreads vmcnt(0) drain (per-wave counter) is
// free. Producers eat the HBM x-load drain once per 4 steps (reg-chunked);
// writers eat the store-ack drain. Each role runs its own loop with an
// IDENTICAL barrier count (1 prologue + 2 per step).
__global__ __launch_bounds__(512, 1)
void augru_pcw(const float* __restrict__ X, const int* __restrict__ SL,
               const float* __restrict__ ATT, const float* __restrict__ Wg,
               const float* __restrict__ bg, const float* __restrict__ Wc,
               const float* __restrict__ bc, float* __restrict__ OUT) {
  __shared__ __align__(16) half_t sAh[2][512];   // h, A-layout fp16
  __shared__ __align__(16) half_t sRh[2][512];   // r*h, A-layout fp16
  __shared__ __align__(16) f32x4 sPre[2][12][64];  // x-preacts, D-layout (24KB)
  __shared__ __align__(16) float sOut[2][16][68];  // f32 h out, padded (8.7KB)
  __shared__ float sAtt[T_][16];                   // att table (12.8KB)

  const int tid = threadIdx.x;
  const int wv = tid >> 6;
  const int l = tid & 63;
  const int b0 = blockIdx.x * 16;
  const int rA = l & 15;
  const int kq = l >> 4;

  int Lm = 1;
  for (int r = 0; r < 16; ++r) {
    const int v = SL[b0 + r];
    Lm = v > Lm ? v : Lm;
  }
  const int Lm4 = (Lm + 3) & ~3;  // T_=200 divisible by 4

  // one-time: att table (coalesced global reads) + zero h staging
  for (int i = tid; i < 16 * T_; i += 512) {
    const int r = i / T_;
    const int t0_ = i - r * T_;
    sAtt[t0_][r] = ATT[(size_t)(b0 + r) * T_ + t0_];
  }
  if (tid < 128) {
    h8 z;
#pragma unroll
    for (int j = 0; j < 8; ++j) z[j] = (half_t)0.f;
    ((h8*)&sAh[0][0])[tid] = z;  // 128 h8 = all 1024 halfs
  }

  if (wv < 4) {
    // ========================= CONSUMERS (4 waves) =========================
    const int w = wv;
    const int rowD = kq * 4;
    const int colW = 16 * w + rA;
    const int ksl = colW >> 5;
    const int c32 = colW & 31;
    const int baseA = (rowD + 16 * (c32 >> 3)) * 8 + (c32 & 7);

    const h8 bgr2 = loadB(Wg, 128, 64 + kq * 8, colW);
    const h8 bgr3 = loadB(Wg, 128, 96 + kq * 8, colW);
    const h8 bgu2 = loadB(Wg, 128, 64 + kq * 8, 64 + colW);
    const h8 bgu3 = loadB(Wg, 128, 96 + kq * 8, 64 + colW);
    const h8 bcc2 = loadB(Wc, 64, 64 + kq * 8, colW);
    const h8 bcc3 = loadB(Wc, 64, 96 + kq * 8, colW);
    const int L0 = SL[b0 + rowD + 0];
    const int L1 = SL[b0 + rowD + 1];
    const int L2 = SL[b0 + rowD + 2];
    const int L3 = SL[b0 + rowD + 3];
    const f32x4 z4 = {0.f, 0.f, 0.f, 0.f};
    float hd0 = 0.f, hd1 = 0.f, hd2 = 0.f, hd3 = 0.f;

    __syncthreads();  // prologue barrier (drains init loads, once)

    for (int tt = 0; tt < Lm4; tt += 4) {
#pragma unroll
      for (int k = 0; k < 4; ++k) {
        const int t = tt + k;
        const int tb = t & 1;
        const h8 ah0 = ((const h8*)&sAh[0][0])[l];
        const h8 ah1 = ((const h8*)&sAh[1][0])[l];
        const f32x4 grx = sPre[tb][w][l];
        const f32x4 gux = sPre[tb][4 + w][l];
        const f32x4 ccx = sPre[tb][8 + w][l];
        const float at0 = sAtt[t][rowD + 0];
        const float at1 = sAtt[t][rowD + 1];
        const float at2 = sAtt[t][rowD + 2];
        const float at3 = sAtt[t][rowD + 3];

        const f32x4 gr = MF(ah0, bgr2, grx) + MF(ah1, bgr3, z4);
        sRh[ksl][baseA + 0] = (half_t)(sigmoidf_(gr[0]) * hd0);
        sRh[ksl][baseA + 8] = (half_t)(sigmoidf_(gr[1]) * hd1);
        sRh[ksl][baseA + 16] = (half_t)(sigmoidf_(gr[2]) * hd2);
        sRh[ksl][baseA + 24] = (half_t)(sigmoidf_(gr[3]) * hd3);
        const f32x4 gu = MF(ah0, bgu2, gux) + MF(ah1, bgu3, z4);

        __syncthreads();  // B1 (no vm ops outstanding -> free drain)

        const h8 arh0 = ((const h8*)&sRh[0][0])[l];
        const h8 arh1 = ((const h8*)&sRh[1][0])[l];
        const f32x4 cc = MF(arh0, bcc2, ccx) + MF(arh1, bcc3, z4);

#define FIN(i, HD, AT, LI)                                         \
  {                                                                \
    const float uv = sigmoidf_(gu[i]);                             \
    const float cv = tanhf_(cc[i]);                                \
    const float hn = fmaf(AT * uv, cv - HD, HD);                   \
    const bool ok = t < LI;                                        \
    HD = ok ? hn : HD;                                             \
    sAh[ksl][baseA + (i)*8] = (half_t)HD;                          \
    sOut[tb][rowD + i][colW] = ok ? HD : 0.0f;                     \
  }
        FIN(0, hd0, at0, L0)
        FIN(1, hd1, at1, L1)
        FIN(2, hd2, at2, L2)
        FIN(3, hd3, at3, L3)
#undef FIN

        __syncthreads();  // B2 (free drain)
      }
    }
  } else if (wv < 6) {
    // ========================= PRODUCERS (2 waves) =========================
    const int p = wv - 4;
    // x-part B-fragments: gate tiles nt=4p..4p+3 (cols nt*16..), cand 2p..2p+1
    const h8 bA0 = loadB(Wg, 128, 0 + kq * 8, (4 * p + 0) * 16 + rA);
    const h8 bB0 = loadB(Wg, 128, 32 + kq * 8, (4 * p + 0) * 16 + rA);
    const h8 bA1 = loadB(Wg, 128, 0 + kq * 8, (4 * p + 1) * 16 + rA);
    const h8 bB1 = loadB(Wg, 128, 32 + kq * 8, (4 * p + 1) * 16 + rA);
    const h8 bA2 = loadB(Wg, 128, 0 + kq * 8, (4 * p + 2) * 16 + rA);
    const h8 bB2 = loadB(Wg, 128, 32 + kq * 8, (4 * p + 2) * 16 + rA);
    const h8 bA3 = loadB(Wg, 128, 0 + kq * 8, (4 * p + 3) * 16 + rA);
    const h8 bB3 = loadB(Wg, 128, 32 + kq * 8, (4 * p + 3) * 16 + rA);
    const h8 cA0 = loadB(Wc, 64, 0 + kq * 8, (2 * p + 0) * 16 + rA);
    const h8 cB0 = loadB(Wc, 64, 32 + kq * 8, (2 * p + 0) * 16 + rA);
    const h8 cA1 = loadB(Wc, 64, 0 + kq * 8, (2 * p + 1) * 16 + rA);
    const h8 cB1 = loadB(Wc, 64, 32 + kq * 8, (2 * p + 1) * 16 + rA);
    const float fb0 = bg[(4 * p + 0) * 16 + rA];
    const float fb1 = bg[(4 * p + 1) * 16 + rA];
    const float fb2 = bg[(4 * p + 2) * 16 + rA];
    const float fb3 = bg[(4 * p + 3) * 16 + rA];
    const float fc0 = bc[(2 * p + 0) * 16 + rA];
    const float fc1 = bc[(2 * p + 1) * 16 + rA];

    const float* __restrict__ xrow = X + (size_t)(b0 + rA) * (T_ * D_);

    // staging regs for 4 steps of x (issued once per 4 steps -> one drain per 4)
    f32x4 stg[16];
#pragma unroll
    for (int j = 0; j < 4; ++j) {
      int s = 1 + j;
      if (s > Lm4 - 1) s = Lm4 - 1;
      stg[4 * j + 0] = *(const f32x4*)(xrow + s * 64 + kq * 8);
      stg[4 * j + 1] = *(const f32x4*)(xrow + s * 64 + kq * 8 + 4);
      stg[4 * j + 2] = *(const f32x4*)(xrow + s * 64 + 32 + kq * 8);
      stg[4 * j + 3] = *(const f32x4*)(xrow + s * 64 + 32 + kq * 8 + 4);
    }

#define PEMIT(AX0, AX1, NB)                                                 \
  {                                                                         \
    f32x4 a;                                                                \
    a = (f32x4){fb0, fb0, fb0, fb0};                                        \
    a = MF(AX0, bA0, a); a = MF(AX1, bB0, a);                               \
    sPre[NB][4 * p + 0][l] = a;                                             \
    a = (f32x4){fb1, fb1, fb1, fb1};                                        \
    a = MF(AX0, bA1, a); a = MF(AX1, bB1, a);                               \
    sPre[NB][4 * p + 1][l] = a;                                             \
    a = (f32x4){fb2, fb2, fb2, fb2};                                        \
    a = MF(AX0, bA2, a); a = MF(AX1, bB2, a);                               \
    sPre[NB][4 * p + 2][l] = a;                                             \
    a = (f32x4){fb3, fb3, fb3, fb3};                                        \
    a = MF(AX0, bA3, a); a = MF(AX1, bB3, a);                               \
    sPre[NB][4 * p + 3][l] = a;                                             \
    a = (f32x4){fc0, fc0, fc0, fc0};                                        \
    a = MF(AX0, cA0, a); a = MF(AX1, cB0, a);                               \
    sPre[NB][8 + 2 * p + 0][l] = a;                                         \
    a = (f32x4){fc1, fc1, fc1, fc1};                                        \
    a = MF(AX0, cA1, a); a = MF(AX1, cB1, a);                               \
    sPre[NB][8 + 2 * p + 1][l] = a;                                         \
  }

    // prologue: pre(0) from a direct x(0) load
    {
      const f32x4 a0 = *(const f32x4*)(xrow + kq * 8);
      const f32x4 a1 = *(const f32x4*)(xrow + kq * 8 + 4);
      const f32x4 a2 = *(const f32x4*)(xrow + 32 + kq * 8);
      const f32x4 a3 = *(const f32x4*)(xrow + 32 + kq * 8 + 4);
      h8 ax0, ax1;
#pragma unroll
      for (int j = 0; j < 4; ++j) {
        ax0[j] = (half_t)a0[j];
        ax0[4 + j] = (half_t)a1[j];
        ax1[j] = (half_t)a2[j];
        ax1[4 + j] = (half_t)a3[j];
      }
      PEMIT(ax0, ax1, 0)
    }

    h8 r0a, r0b, r1a, r1b, r2a, r2b, r3a, r3b;  // 4-step x ring (fp16 frags)

    __syncthreads();  // prologue barrier (drains staging issue, once)

    for (int tt = 0; tt < Lm4; tt += 4) {
#pragma unroll
      for (int k = 0; k < 4; ++k) {
        const int t = tt + k;
        if (k == 0) {
          // cvt staged x(tt+1..tt+4) -> ring
#define CVT8(D0, D1, S0, S1, S2, S3)                      \
  {                                                       \
    _Pragma("unroll") for (int j = 0; j < 4; ++j) {       \
      D0[j] = (half_t)S0[j];                              \
      D0[4 + j] = (half_t)S1[j];                          \
      D1[j] = (half_t)S2[j];                              \
      D1[4 + j] = (half_t)S3[j];                          \
    }                                                     \
  }
          CVT8(r0a, r0b, stg[0], stg[1], stg[2], stg[3])
          CVT8(r1a, r1b, stg[4], stg[5], stg[6], stg[7])
          CVT8(r2a, r2b, stg[8], stg[9], stg[10], stg[11])
          CVT8(r3a, r3b, stg[12], stg[13], stg[14], stg[15])
#undef CVT8
        }
        h8 ax0, ax1;
        if (k == 0) { ax0 = r0a; ax1 = r0b; }
        else if (k == 1) { ax0 = r1a; ax1 = r1b; }
        else if (k == 2) { ax0 = r2a; ax1 = r2b; }
        else { ax0 = r3a; ax1 = r3b; }

        const int nb = (t + 1) & 1;
        PEMIT(ax0, ax1, nb)

        if (k == 1) {  // issue next 4-step chunk (x(tt+5..tt+8), clamped)
#pragma unroll
          for (int j = 0; j < 4; ++j) {
            int s = tt + 5 + j;
            if (s > T_ - 1) s = T_ - 1;
            stg[4 * j + 0] = *(const f32x4*)(xrow + s * 64 + kq * 8);
            stg[4 * j + 1] = *(const f32x4*)(xrow + s * 64 + kq * 8 + 4);
            stg[4 * j + 2] = *(const f32x4*)(xrow + s * 64 + 32 + kq * 8);
            stg[4 * j + 3] = *(const f32x4*)(xrow + s * 64 + 32 + kq * 8 + 4);
          }
        }
        __syncthreads();  // B1
        __syncthreads();  // B2
      }
    }
#undef PEMIT
  } else {
    // ========================= WRITERS (2 waves) ===========================
    const int wr = wv - 6;
    const int gr_ = wr * 8 + (l >> 3);   // output batch row 0..15
    const int c8_ = (l & 7) * 8;         // output col octet
    float* __restrict__ orow_w = OUT + (size_t)(b0 + gr_) * (T_ * D_) + c8_;
    const f32x4 zf4 = {0.f, 0.f, 0.f, 0.f};

    __syncthreads();  // prologue barrier

    for (int tt = 0; tt < Lm4; tt += 4) {
#pragma unroll
      for (int k = 0; k < 4; ++k) {
        const int t = tt + k;
        __syncthreads();  // B1
        if (t > 0) {
          const int pb = (t - 1) & 1;
          const f32x4 v0 = *(const f32x4*)&sOut[pb][gr_][c8_];
          const f32x4 v1 = *(const f32x4*)&sOut[pb][gr_][c8_ + 4];
          *(f32x4*)(orow_w + (size_t)(t - 1) * 64) = v0;
          *(f32x4*)(orow_w + (size_t)(t - 1) * 64 + 4) = v1;
        }
        __syncthreads();  // B2 (store drain lands here, off the chain)
      }
    }
    // flush last step + zero-fill tail
    {
      const int pb = (Lm4 - 1) & 1;
      const f32x4 v0 = *(const f32x4*)&sOut[pb][gr_][c8_];
      const f32x4 v1 = *(const f32x4*)&sOut[pb][gr_][c8_ + 4];
      *(f32x4*)(orow_w + (size_t)(Lm4 - 1) * 64) = v0;
      *(f32x4*)(orow_w + (size_t)(Lm4 - 1) * 64 + 4) = v1;
      for (int tz = Lm4; tz < T_; ++tz) {
        *(f32x4*)(orow_w + (size_t)tz * 64) = zf4;
        *(f32x4*)(orow_w + (size_t)tz * 64 + 4) = zf4;
      }
    }
  }
}

extern "C" void kernel_launch(void* const* d_in, const int* in_sizes, int n_in,
                              void* d_out, int out_size, void* d_ws, size_t ws_size,
                              hipStream_t stream) {
  (void)in_sizes; (void)n_in; (void)d_ws; (void)ws_size; (void)out_size;
  const float* X  = (const float*)d_in[0];
  const int*   SL = (const int*)d_in[1];
  const float* A  = (const float*)d_in[2];
  const float* Wg = (const float*)d_in[3];
  const float* bg = (const float*)d_in[4];
  const float* Wc = (const float*)d_in[5];
  const float* bc = (const float*)d_in[6];
  float* O = (float*)d_out;

  augru_pcw<<<NBLK, 512, 0, stream>>>(X, SL, A, Wg, bg, Wc, bc, O);
}

// Round 19
// 127.892 us; speedup vs baseline: 2.0925x; 1.0061x over previous
//
#include <hip/hip_runtime.h>

#define B_ 2048
#define T_ 200
#define D_ 64

constexpr int NBLK = B_ / 16;  // 128 blocks, 8 waves each

typedef _Float16 half_t;
typedef __attribute__((ext_vector_type(8))) _Float16 h8;
typedef __attribute__((ext_vector_type(4))) float f32x4;

// 16x16x32 f16 MFMA fragment layouts [HW-verified r9/r11/r12]:
// A: lane l holds A[row=l&15][k=(l>>4)*8+j]
// B: lane l holds B[k=(l>>4)*8+j][col=l&15]
// C/D: lane l holds D[row=(l>>4)*4+reg][col=l&15]
__device__ __forceinline__ f32x4 MF(h8 a, h8 b, f32x4 c) {
  return __builtin_amdgcn_mfma_f32_16x16x32_f16(a, b, c, 0, 0, 0);
}

__device__ __forceinline__ float rcp_(float x) { return __builtin_amdgcn_rcpf(x); }
__device__ __forceinline__ float sigmoidf_(float x) { return rcp_(1.0f + __expf(-x)); }
__device__ __forceinline__ float tanhf_(float x) {
  x = fminf(fmaxf(x, -15.0f), 15.0f);
  const float e = __expf(2.0f * x);
  return (e - 1.0f) * rcp_(e + 1.0f);
}

__device__ __forceinline__ h8 loadB(const float* __restrict__ W, int stride,
                                    int k0, int col) {
  h8 v;
#pragma unroll
  for (int j = 0; j < 8; ++j) v[j] = (half_t)W[(k0 + j) * stride + col];
  return v;
}

// Raw barrier for producer/writer waves ONLY: drains LDS (lgkmcnt) for
// cross-wave visibility but leaves global loads/stores in flight — kills the
// stg-prefetch drain (r18's residual pole). Consumers keep __syncthreads
// (they have zero in-loop VMEM, so its vmcnt(0) is free, and the intrinsic
// doesn't pin the chain scheduling the way r14's asm did).
#define RBAR() asm volatile("s_waitcnt lgkmcnt(0)\n\ts_barrier" ::: "memory")

__global__ __launch_bounds__(512, 1)
void augru_pcw(const float* __restrict__ X, const int* __restrict__ SL,
               const float* __restrict__ ATT, const float* __restrict__ Wg,
               const float* __restrict__ bg, const float* __restrict__ Wc,
               const float* __restrict__ bc, float* __restrict__ OUT) {
  __shared__ __align__(16) half_t sAh[2][512];     // h, A-layout fp16
  __shared__ __align__(16) half_t sRh[2][512];     // r*h, A-layout fp16
  __shared__ __align__(16) f32x4 sPre[2][12][64];  // x-preacts, D-layout (24KB)
  __shared__ __align__(16) float sOut[2][16][68];  // f32 h out, padded (8.7KB)
  __shared__ __align__(16) float sAtt[T_][16];     // att table (12.8KB)

  const int tid = threadIdx.x;
  const int wv = tid >> 6;
  const int l = tid & 63;
  const int b0 = blockIdx.x * 16;
  const int rA = l & 15;
  const int kq = l >> 4;

  int Lm = 1;
  for (int r = 0; r < 16; ++r) {
    const int v = SL[b0 + r];
    Lm = v > Lm ? v : Lm;
  }
  const int Lm4 = (Lm + 3) & ~3;

  // one-time: att table (coalesced) + zero h staging
  for (int i = tid; i < 16 * T_; i += 512) {
    const int r = i / T_;
    const int t0_ = i - r * T_;
    sAtt[t0_][r] = ATT[(size_t)(b0 + r) * T_ + t0_];
  }
  if (tid < 128) {
    h8 z;
#pragma unroll
    for (int j = 0; j < 8; ++j) z[j] = (half_t)0.f;
    ((h8*)&sAh[0][0])[tid] = z;
  }

  if (wv < 4) {
    // ========================= CONSUMERS (4 waves) =========================
    const int w = wv;
    const int rowD = kq * 4;
    const int colW = 16 * w + rA;
    const int ksl = colW >> 5;
    const int c32 = colW & 31;
    const int baseA = (rowD + 16 * (c32 >> 3)) * 8 + (c32 & 7);

    const h8 bgr2 = loadB(Wg, 128, 64 + kq * 8, colW);
    const h8 bgr3 = loadB(Wg, 128, 96 + kq * 8, colW);
    const h8 bgu2 = loadB(Wg, 128, 64 + kq * 8, 64 + colW);
    const h8 bgu3 = loadB(Wg, 128, 96 + kq * 8, 64 + colW);
    const h8 bcc2 = loadB(Wc, 64, 64 + kq * 8, colW);
    const h8 bcc3 = loadB(Wc, 64, 96 + kq * 8, colW);
    const int L0 = SL[b0 + rowD + 0];
    const int L1 = SL[b0 + rowD + 1];
    const int L2 = SL[b0 + rowD + 2];
    const int L3 = SL[b0 + rowD + 3];
    const f32x4 z4 = {0.f, 0.f, 0.f, 0.f};
    float hd0 = 0.f, hd1 = 0.f, hd2 = 0.f, hd3 = 0.f;

    __syncthreads();  // prologue

    for (int tt = 0; tt < Lm4; tt += 4) {
#pragma unroll
      for (int k = 0; k < 4; ++k) {
        const int t = tt + k;
        const int tb = t & 1;
        const h8 ah0 = ((const h8*)&sAh[0][0])[l];
        const h8 ah1 = ((const h8*)&sAh[1][0])[l];
        const f32x4 grx = sPre[tb][w][l];
        const f32x4 gux = sPre[tb][4 + w][l];
        const f32x4 ccx = sPre[tb][8 + w][l];
        const f32x4 atv = *(const f32x4*)&sAtt[t][rowD];  // broadcast b128

        const f32x4 gr = MF(ah0, bgr2, grx) + MF(ah1, bgr3, z4);
        sRh[ksl][baseA + 0] = (half_t)(sigmoidf_(gr[0]) * hd0);
        sRh[ksl][baseA + 8] = (half_t)(sigmoidf_(gr[1]) * hd1);
        sRh[ksl][baseA + 16] = (half_t)(sigmoidf_(gr[2]) * hd2);
        sRh[ksl][baseA + 24] = (half_t)(sigmoidf_(gr[3]) * hd3);

        // u gate + its sigmoid + att scale: all phase-1 (off the rh path)
        const f32x4 gu = MF(ah0, bgu2, gux) + MF(ah1, bgu3, z4);
        const float ua0 = atv[0] * sigmoidf_(gu[0]);
        const float ua1 = atv[1] * sigmoidf_(gu[1]);
        const float ua2 = atv[2] * sigmoidf_(gu[2]);
        const float ua3 = atv[3] * sigmoidf_(gu[3]);

        __syncthreads();  // B1 (free: no VMEM outstanding)

        const h8 arh0 = ((const h8*)&sRh[0][0])[l];
        const h8 arh1 = ((const h8*)&sRh[1][0])[l];
        const f32x4 cc = MF(arh0, bcc2, ccx) + MF(arh1, bcc3, z4);

#define FIN(i, HD, UA, LI)                                         \
  {                                                                \
    const float cv = tanhf_(cc[i]);                                \
    const float hn = fmaf(UA, cv - HD, HD);                        \
    const bool ok = t < LI;                                        \
    HD = ok ? hn : HD;                                             \
    sAh[ksl][baseA + (i)*8] = (half_t)HD;                          \
    sOut[tb][rowD + i][colW] = ok ? HD : 0.0f;                     \
  }
        FIN(0, hd0, ua0, L0)
        FIN(1, hd1, ua1, L1)
        FIN(2, hd2, ua2, L2)
        FIN(3, hd3, ua3, L3)
#undef FIN

        __syncthreads();  // B2 (free)
      }
    }
  } else if (wv < 6) {
    // ========================= PRODUCERS (2 waves) =========================
    const int p = wv - 4;
    const h8 bA0 = loadB(Wg, 128, 0 + kq * 8, (4 * p + 0) * 16 + rA);
    const h8 bB0 = loadB(Wg, 128, 32 + kq * 8, (4 * p + 0) * 16 + rA);
    const h8 bA1 = loadB(Wg, 128, 0 + kq * 8, (4 * p + 1) * 16 + rA);
    const h8 bB1 = loadB(Wg, 128, 32 + kq * 8, (4 * p + 1) * 16 + rA);
    const h8 bA2 = loadB(Wg, 128, 0 + kq * 8, (4 * p + 2) * 16 + rA);
    const h8 bB2 = loadB(Wg, 128, 32 + kq * 8, (4 * p + 2) * 16 + rA);
    const h8 bA3 = loadB(Wg, 128, 0 + kq * 8, (4 * p + 3) * 16 + rA);
    const h8 bB3 = loadB(Wg, 128, 32 + kq * 8, (4 * p + 3) * 16 + rA);
    const h8 cA0 = loadB(Wc, 64, 0 + kq * 8, (2 * p + 0) * 16 + rA);
    const h8 cB0 = loadB(Wc, 64, 32 + kq * 8, (2 * p + 0) * 16 + rA);
    const h8 cA1 = loadB(Wc, 64, 0 + kq * 8, (2 * p + 1) * 16 + rA);
    const h8 cB1 = loadB(Wc, 64, 32 + kq * 8, (2 * p + 1) * 16 + rA);
    const float fb0 = bg[(4 * p + 0) * 16 + rA];
    const float fb1 = bg[(4 * p + 1) * 16 + rA];
    const float fb2 = bg[(4 * p + 2) * 16 + rA];
    const float fb3 = bg[(4 * p + 3) * 16 + rA];
    const float fc0 = bc[(2 * p + 0) * 16 + rA];
    const float fc1 = bc[(2 * p + 1) * 16 + rA];

    const float* __restrict__ xrow = X + (size_t)(b0 + rA) * (T_ * D_);

    f32x4 stg[16];
#pragma unroll
    for (int j = 0; j < 4; ++j) {
      int s = 1 + j;
      if (s > Lm4 - 1) s = Lm4 - 1;
      stg[4 * j + 0] = *(const f32x4*)(xrow + s * 64 + kq * 8);
      stg[4 * j + 1] = *(const f32x4*)(xrow + s * 64 + kq * 8 + 4);
      stg[4 * j + 2] = *(const f32x4*)(xrow + s * 64 + 32 + kq * 8);
      stg[4 * j + 3] = *(const f32x4*)(xrow + s * 64 + 32 + kq * 8 + 4);
    }

    // first half of the 12 preact outputs (phase 1)
#define PEMIT1(AX0, AX1, NB)                          \
  {                                                   \
    f32x4 a;                                          \
    a = (f32x4){fb0, fb0, fb0, fb0};                  \
    a = MF(AX0, bA0, a); a = MF(AX1, bB0, a);         \
    sPre[NB][4 * p + 0][l] = a;                       \
    a = (f32x4){fb1, fb1, fb1, fb1};                  \
    a = MF(AX0, bA1, a); a = MF(AX1, bB1, a);         \
    sPre[NB][4 * p + 1][l] = a;                       \
    a = (f32x4){fc0, fc0, fc0, fc0};                  \
    a = MF(AX0, cA0, a); a = MF(AX1, cB0, a);         \
    sPre[NB][8 + 2 * p + 0][l] = a;                   \
  }
    // second half (phase 2)
#define PEMIT2(AX0, AX1, NB)                          \
  {                                                   \
    f32x4 a;                                          \
    a = (f32x4){fb2, fb2, fb2, fb2};                  \
    a = MF(AX0, bA2, a); a = MF(AX1, bB2, a);         \
    sPre[NB][4 * p + 2][l] = a;                       \
    a = (f32x4){fb3, fb3, fb3, fb3};                  \
    a = MF(AX0, bA3, a); a = MF(AX1, bB3, a);         \
    sPre[NB][4 * p + 3][l] = a;                       \
    a = (f32x4){fc1, fc1, fc1, fc1};                  \
    a = MF(AX0, cA1, a); a = MF(AX1, cB1, a);         \
    sPre[NB][8 + 2 * p + 1][l] = a;                   \
  }

    // prologue: pre(0) -> buf0 (both halves)
    {
      const f32x4 a0 = *(const f32x4*)(xrow + kq * 8);
      const f32x4 a1 = *(const f32x4*)(xrow + kq * 8 + 4);
      const f32x4 a2 = *(const f32x4*)(xrow + 32 + kq * 8);
      const f32x4 a3 = *(const f32x4*)(xrow + 32 + kq * 8 + 4);
      h8 ax0, ax1;
#pragma unroll
      for (int j = 0; j < 4; ++j) {
        ax0[j] = (half_t)a0[j];
        ax0[4 + j] = (half_t)a1[j];
        ax1[j] = (half_t)a2[j];
        ax1[4 + j] = (half_t)a3[j];
      }
      PEMIT1(ax0, ax1, 0)
      PEMIT2(ax0, ax1, 0)
    }

    h8 r0a, r0b, r1a, r1b, r2a, r2b, r3a, r3b;

    RBAR();  // prologue barrier

    for (int tt = 0; tt < Lm4; tt += 4) {
#pragma unroll
      for (int k = 0; k < 4; ++k) {
        const int t = tt + k;
        if (k == 0) {
#define CVT8(D0, D1, S0, S1, S2, S3)                      \
  {                                                       \
    _Pragma("unroll") for (int j = 0; j < 4; ++j) {       \
      D0[j] = (half_t)S0[j];                              \
      D0[4 + j] = (half_t)S1[j];                          \
      D1[j] = (half_t)S2[j];                              \
      D1[4 + j] = (half_t)S3[j];                          \
    }                                                     \
  }
          CVT8(r0a, r0b, stg[0], stg[1], stg[2], stg[3])
          CVT8(r1a, r1b, stg[4], stg[5], stg[6], stg[7])
          CVT8(r2a, r2b, stg[8], stg[9], stg[10], stg[11])
          CVT8(r3a, r3b, stg[12], stg[13], stg[14], stg[15])
#undef CVT8
        }
        h8 ax0, ax1;
        if (k == 0) { ax0 = r0a; ax1 = r0b; }
        else if (k == 1) { ax0 = r1a; ax1 = r1b; }
        else if (k == 2) { ax0 = r2a; ax1 = r2b; }
        else { ax0 = r3a; ax1 = r3b; }

        const int nb = (t + 1) & 1;
        PEMIT1(ax0, ax1, nb)

        RBAR();  // B1 (stg loads stay in flight)

        PEMIT2(ax0, ax1, nb)

        if (k == 1) {  // next 4-step x chunk (clamped); never drained in-loop
#pragma unroll
          for (int j = 0; j < 4; ++j) {
            int s = tt + 5 + j;
            if (s > T_ - 1) s = T_ - 1;
            stg[4 * j + 0] = *(const f32x4*)(xrow + s * 64 + kq * 8);
            stg[4 * j + 1] = *(const f32x4*)(xrow + s * 64 + kq * 8 + 4);
            stg[4 * j + 2] = *(const f32x4*)(xrow + s * 64 + 32 + kq * 8);
            stg[4 * j + 3] = *(const f32x4*)(xrow + s * 64 + 32 + kq * 8 + 4);
          }
        }
        RBAR();  // B2
      }
    }
#undef PEMIT1
#undef PEMIT2
  } else {
    // ========================= WRITERS (2 waves) ===========================
    const int wr = wv - 6;
    const int gr_ = wr * 8 + (l >> 3);
    const int c8_ = (l & 7) * 8;
    float* __restrict__ orow_w = OUT + (size_t)(b0 + gr_) * (T_ * D_) + c8_;
    const f32x4 zf4 = {0.f, 0.f, 0.f, 0.f};

    RBAR();  // prologue barrier

    for (int tt = 0; tt < Lm4; tt += 4) {
#pragma unroll
      for (int k = 0; k < 4; ++k) {
        const int t = tt + k;
        RBAR();  // B1
        if (t > 0) {
          const int pb = (t - 1) & 1;
          const f32x4 v0 = *(const f32x4*)&sOut[pb][gr_][c8_];
          const f32x4 v1 = *(const f32x4*)&sOut[pb][gr_][c8_ + 4];
          *(f32x4*)(orow_w + (size_t)(t - 1) * 64) = v0;
          *(f32x4*)(orow_w + (size_t)(t - 1) * 64 + 4) = v1;
        }
        RBAR();  // B2 (store-acks never drained in-loop)
      }
    }
    // flush last step + zero-fill tail
    {
      const int pb = (Lm4 - 1) & 1;
      const f32x4 v0 = *(const f32x4*)&sOut[pb][gr_][c8_];
      const f32x4 v1 = *(const f32x4*)&sOut[pb][gr_][c8_ + 4];
      *(f32x4*)(orow_w + (size_t)(Lm4 - 1) * 64) = v0;
      *(f32x4*)(orow_w + (size_t)(Lm4 - 1) * 64 + 4) = v1;
      for (int tz = Lm4; tz < T_; ++tz) {
        *(f32x4*)(orow_w + (size_t)tz * 64) = zf4;
        *(f32x4*)(orow_w + (size_t)tz * 64 + 4) = zf4;
      }
    }
  }
}

extern "C" void kernel_launch(void* const* d_in, const int* in_sizes, int n_in,
                              void* d_out, int out_size, void* d_ws, size_t ws_size,
                              hipStream_t stream) {
  (void)in_sizes; (void)n_in; (void)d_ws; (void)ws_size; (void)out_size;
  const float* X  = (const float*)d_in[0];
  const int*   SL = (const int*)d_in[1];
  const float* A  = (const float*)d_in[2];
  const float* Wg = (const float*)d_in[3];
  const float* bg = (const float*)d_in[4];
  const float* Wc = (const float*)d_in[5];
  const float* bc = (const float*)d_in[6];
  float* O = (float*)d_out;

  augru_pcw<<<NBLK, 512, 0, stream>>>(X, SL, A, Wg, bg, Wc, bc, O);
}